// Round 9
// baseline (249.800 us; speedup 1.0000x reference)
//
#include <hip/hip_runtime.h>

#define B_  2
#define S_  2048
#define D_  1024
#define H_  16
#define HD_ 64
#define M_  (B_*S_)

typedef __bf16 bf16x8 __attribute__((ext_vector_type(8)));
typedef float  f32x4  __attribute__((ext_vector_type(4)));
typedef float  f32x16 __attribute__((ext_vector_type(16)));
typedef unsigned short ushort_t;

static __device__ __forceinline__ ushort_t f2bf(float f) {
  __bf16 b = (__bf16)f;
  return __builtin_bit_cast(ushort_t, b);
}
static __device__ __forceinline__ float bf2f(ushort_t u) {
  return (float)__builtin_bit_cast(__bf16, u);
}

typedef __attribute__((address_space(1))) const unsigned u32g;
typedef __attribute__((address_space(3))) unsigned u32l;
// async global->LDS DMA, 16B/lane; LDS dest = wave-uniform base + lane*16
static __device__ __forceinline__ void gll16(const ushort_t* g, __bf16* l) {
  __builtin_amdgcn_global_load_lds((u32g*)g, (u32l*)l, 16, 0, 0);
}

// ---------------------------------------------------------------------------
// x (fp32 [M][D]) -> bf16 same layout. 8 elems/thread.
// ---------------------------------------------------------------------------
__global__ __launch_bounds__(256) void convert_x(const float* __restrict__ x,
                                                 ushort_t* __restrict__ xb) {
  size_t e = ((size_t)blockIdx.x * 256 + threadIdx.x) * 8;
  float4 a = *(const float4*)(x + e);
  float4 b = *(const float4*)(x + e + 4);
  uint4 pk;
  pk.x = (unsigned)f2bf(a.x) | ((unsigned)f2bf(a.y) << 16);
  pk.y = (unsigned)f2bf(a.z) | ((unsigned)f2bf(a.w) << 16);
  pk.z = (unsigned)f2bf(b.x) | ((unsigned)f2bf(b.y) << 16);
  pk.w = (unsigned)f2bf(b.z) | ((unsigned)f2bf(b.w) << 16);
  *(uint4*)(xb + e) = pk;
}

// ---------------------------------------------------------------------------
// W [K][N] fp32 -> Wt [N][K] bf16 (transposed), 64x64 LDS tile.
// z 0..2 -> Wq/Wk/Wv into Wqkvt ; z=3 -> Wo into Wot.
// ---------------------------------------------------------------------------
__global__ __launch_bounds__(256) void transpose_w(const float* __restrict__ Wq,
                                                   const float* __restrict__ Wk,
                                                   const float* __restrict__ Wv,
                                                   const float* __restrict__ Wo,
                                                   ushort_t* __restrict__ Wqkvt,
                                                   ushort_t* __restrict__ Wot) {
  __shared__ __bf16 T[64][72];
  const int z = blockIdx.z;
  const float* W = (z == 0) ? Wq : (z == 1) ? Wk : (z == 2) ? Wv : Wo;
  ushort_t* Wt = (z < 3) ? (Wqkvt + (size_t)z * 1048576) : Wot;
  const int k0 = blockIdx.y * 64, n0 = blockIdx.x * 64;
  const int t = threadIdx.x, r = t >> 2, c16 = (t & 3) * 16;
#pragma unroll
  for (int i = 0; i < 4; i++) {
    float4 v = *(const float4*)(W + (size_t)(k0 + r) * D_ + n0 + c16 + i * 4);
    T[r][c16 + i*4 + 0] = (__bf16)v.x;
    T[r][c16 + i*4 + 1] = (__bf16)v.y;
    T[r][c16 + i*4 + 2] = (__bf16)v.z;
    T[r][c16 + i*4 + 3] = (__bf16)v.w;
  }
  __syncthreads();
  ushort_t vals[16];
#pragma unroll
  for (int i = 0; i < 16; i++) vals[i] = __builtin_bit_cast(ushort_t, T[c16 + i][r]);
  ushort_t* dst = Wt + (size_t)(n0 + r) * D_ + k0 + c16;
  *(uint4*)dst       = *(const uint4*)&vals[0];
  *(uint4*)(dst + 8) = *(const uint4*)&vals[8];
}

// ---------------------------------------------------------------------------
// V (B,H,S,64) bf16 -> Vtg (B,H,64,S) with key-interleave within each 64-key
// tile: column c holds key ((c&1)<<5)|(c>>1).  Must match attn32's P layout.
// ---------------------------------------------------------------------------
__global__ __launch_bounds__(256) void transpose_v(const ushort_t* __restrict__ Vb,
                                                   ushort_t* __restrict__ Vtg) {
  __shared__ __bf16 T[64][72];
  const int bh = blockIdx.y, kt = blockIdx.x;
  const int t = threadIdx.x, r = t >> 2, c16 = (t & 3) * 16;
  const ushort_t* src = Vb + ((size_t)bh * S_ + kt*64 + r) * 64 + c16;
  *(uint4*)&T[r][c16]     = *(const uint4*)src;
  *(uint4*)&T[r][c16 + 8] = *(const uint4*)(src + 8);
  __syncthreads();
  ushort_t vals[16];
#pragma unroll
  for (int i = 0; i < 16; i++) {
    int c = c16 + i;
    int k = ((c & 1) << 5) | (c >> 1);
    vals[i] = __builtin_bit_cast(ushort_t, T[k][r]);
  }
  ushort_t* dst = Vtg + ((size_t)bh * 64 + r) * S_ + kt*64 + c16;
  *(uint4*)dst       = *(const uint4*)&vals[0];
  *(uint4*)(dst + 8) = *(const uint4*)&vals[8];
}

// ---------------------------------------------------------------------------
// bf16 GEMM, OPERAND-SWAPPED: D[f][s] = Wt[f][k] * X[s][k].
// A-operand = weights (features), B-operand = samples.
// OMODE 0: out[s][f] fp32, direct float4 stores.
// OMODE 1: Q/K/V (B,H,S,64) bf16 via in-register RoPE + XOR-swizzled LDS
//          transpose -> fully coalesced uint4 store bursts.
// ---------------------------------------------------------------------------
template<int OMODE, int BS>
__global__ __launch_bounds__(256) void gemm_bf16(const ushort_t* __restrict__ Wt,
                                                 const ushort_t* __restrict__ X,
                                                 void* __restrict__ Cp,
                                                 const float* __restrict__ cosb,
                                                 const float* __restrict__ sinb) {
  constexpr int NT = BS / 32;                    // sample frags per wave
  constexpr int SM = (OMODE == 1) ? 16384 : 6144;
  __shared__ __bf16 SMEM[SM];
  __bf16* As = SMEM;                             // [128][32] weights
  __bf16* Bs = SMEM + 4096;                      // [BS][32] samples
  const int t = threadIdx.x, w = t >> 6, lane = t & 63, l15 = lane & 15, g = lane >> 4;
  const int wr = w >> 1, wc = w & 1;
  const int f0 = blockIdx.y * 128, s0 = blockIdx.x * BS;
  const int al = lane >> 2, ac = (lane & 3) * 8; // DMA lane coords
  f32x4 acc[4][NT] = {};

  for (int k0 = 0; k0 < D_; k0 += 32) {
    __syncthreads();
#pragma unroll
    for (int i = 0; i < 2; i++)
      gll16(Wt + (size_t)(f0 + i*64 + w*16 + al) * D_ + k0 + ac, &As[i*2048 + w*512]);
#pragma unroll
    for (int i = 0; i < BS/64; i++)
      gll16(X + (size_t)(s0 + i*64 + w*16 + al) * D_ + k0 + ac, &Bs[i*2048 + w*512]);
    __syncthreads();
    bf16x8 af[4], bfv[NT];
#pragma unroll
    for (int mt = 0; mt < 4; mt++)  af[mt]  = *(const bf16x8*)&As[(wr*64 + mt*16 + l15)*32 + g*8];
#pragma unroll
    for (int nt = 0; nt < NT; nt++) bfv[nt] = *(const bf16x8*)&Bs[(wc*(BS/2) + nt*16 + l15)*32 + g*8];
#pragma unroll
    for (int mt = 0; mt < 4; mt++)
#pragma unroll
      for (int nt = 0; nt < NT; nt++)
        acc[mt][nt] = __builtin_amdgcn_mfma_f32_16x16x32_bf16(af[mt], bfv[nt], acc[mt][nt], 0, 0, 0);
  }

  if (OMODE == 0) {
#pragma unroll
    for (int mt = 0; mt < 4; mt++)
#pragma unroll
      for (int nt = 0; nt < NT; nt++) {
        int s = s0 + wc*(BS/2) + nt*16 + l15;
        int f = f0 + wr*64 + mt*16 + g*4;
        *(float4*)&((float*)Cp)[(size_t)s * D_ + f] = *(float4*)&acc[mt][nt];
      }
  } else {
    const int hid = blockIdx.y*2 + wr;           // global head slot 0..47
    const int mat = hid >> 4, h = hid & 15;
    const int s0w = s0 + wc*64;
    ushort_t* dst = (ushort_t*)Cp + (size_t)mat * 4194304;
    const float QS = 0.125f * 1.4426950408889634f;
    if (mat < 2) {   // fused RoPE on fp32 acc (d pairs: mt <-> mt+2)
#pragma unroll
      for (int mt = 0; mt < 2; mt++)
#pragma unroll
        for (int nt = 0; nt < 4; nt++) {
          int s  = s0w + nt*16 + l15;
          int sq = s & (S_ - 1);        // cos/sin indexed by seq pos
          float4 c4 = *(const float4*)&cosb[sq*32 + mt*16 + g*4];
          float4 s4 = *(const float4*)&sinb[sq*32 + mt*16 + g*4];
          const float* cf = (const float*)&c4;
          const float* sf = (const float*)&s4;
#pragma unroll
          for (int r = 0; r < 4; r++) {
            float v1 = acc[mt][nt][r], v2 = acc[mt+2][nt][r];
            float r1 = v1*cf[r] - v2*sf[r];
            float r2 = v2*cf[r] + v1*sf[r];
            if (mat == 0) { r1 *= QS; r2 *= QS; }
            acc[mt][nt][r] = r1; acc[mt+2][nt][r] = r2;
          }
        }
    }
    __syncthreads();                 // staging reads done; reuse SMEM as Tw
    __bf16* Tw = SMEM + w*4096;      // per-wave 64s x 64d, XOR-swizzled chunks
#pragma unroll
    for (int mt = 0; mt < 4; mt++)
#pragma unroll
      for (int nt = 0; nt < 4; nt++) {
        int s_loc = nt*16 + l15;
        int d0 = mt*16 + g*4;
        int ch = (d0 >> 3) ^ (s_loc & 7);
        ushort_t pk[4];
#pragma unroll
        for (int r = 0; r < 4; r++) pk[r] = f2bf(acc[mt][nt][r]);
        *(ushort4*)&Tw[s_loc*64 + ch*8 + (d0 & 7)] = *(const ushort4*)pk;
      }
    // wave-private region: in-wave LDS ordering suffices, no barrier
#pragma unroll
    for (int j = 0; j < 8; j++) {
      int s_loc = j*8 + (lane >> 3);
      int ci = lane & 7;
      int ch = ci ^ (s_loc & 7);
      uint4 v = *(const uint4*)&Tw[s_loc*64 + ch*8];
      int s = s0w + s_loc;
      int b = s >> 11, srow = s & (S_ - 1);
      *(uint4*)&dst[(((size_t)(b*H_ + h) * S_ + srow) << 6) + ci*8] = v;
    }
  }
}

// ---------------------------------------------------------------------------
// Flash attention, split-K x2, 64 Q-ROWS PER WAVE (256 q/block):
//  - K/V B-frags read once per iter, reused across 2 q-subtiles -> LDS
//    bytes per MFMA cut 1.75x (the measured bottleneck: LDS pipe ~66% busy)
//  - double-buffered 64-key tiles via global_load_lds DMA; DMA(t+1) issued
//    before s_waitcnt vmcnt(4) + s_barrier (async pipeline)
//  - XOR-swizzled unpadded LDS; fixed-max softmax; deferred l reduction
// Grid (8,32,2) = 512 blocks = exactly 2/CU. LDS 16K+16K+32K = 64 KB.
// C/D 32x32 layout (m74/m101): col=lane&31, row=(reg&3)+8*(reg>>2)+4*(lane>>5).
// ---------------------------------------------------------------------------
__global__ __launch_bounds__(256) void attn32(const ushort_t* __restrict__ Q,
                                              const ushort_t* __restrict__ K,
                                              const ushort_t* __restrict__ Vtg,
                                              ushort_t* __restrict__ op0,
                                              ushort_t* __restrict__ op1,
                                              float* __restrict__ lw) {
  __shared__ __bf16 KsL[2][64 * 64];
  __shared__ __bf16 VtL[2][64 * 64];
  __shared__ __bf16 Ps[4][64 * 64];
  const int t = threadIdx.x, w = t >> 6, lane = t & 63;
  const int l31 = lane & 31, h2 = lane >> 5, sw = l31 & 7;
  const int bh = blockIdx.y, q0 = blockIdx.x * 256 + w * 64, z = blockIdx.z;

  // Q A-frags for 2 q-subtiles of 32 rows x 4 k-chunks
  bf16x8 qf[8];
#pragma unroll
  for (int qs = 0; qs < 2; qs++)
#pragma unroll
    for (int kc = 0; kc < 4; kc++)
      qf[qs*4 + kc] = *(const bf16x8*)(Q + ((size_t)bh * S_ + q0 + qs*32 + l31) * HD_ + kc*16 + h2*8);

  f32x16 o[4] = {};          // [qs][dsub]
  float lp[2][16];
#pragma unroll
  for (int qs = 0; qs < 2; qs++)
#pragma unroll
    for (int i = 0; i < 16; i++) lp[qs][i] = 0.f;

  const ushort_t* Kb = K   + ((size_t)bh * S_ + z * 1024) * HD_;
  const ushort_t* Vg = Vtg + (size_t)bh * HD_ * S_ + z * 1024;
  const int krl = lane >> 3;                  // row-in-DMA 0..7
  const int kco = ((lane & 7) ^ krl) * 8;     // swizzled chunk (elems)

  // drain Q loads so in-loop vmcnt counts only DMAs
  asm volatile("s_waitcnt vmcnt(0)" ::: "memory");

#define STAGE(KT, CB)                                                        \
  {                                                                          \
    _Pragma("unroll")                                                        \
    for (int p = 0; p < 2; p++) {                                            \
      int bk = w*8 + p*32;                                                   \
      gll16(Kb + (size_t)((KT)*64 + bk + krl) * HD_ + kco, &KsL[CB][bk*64]); \
    }                                                                        \
    _Pragma("unroll")                                                        \
    for (int p = 0; p < 2; p++) {                                            \
      int bd = w*8 + p*32;                                                   \
      gll16(Vg + (size_t)(bd + krl) * S_ + (KT)*64 + kco, &VtL[CB][bd*64]);  \
    }                                                                        \
  }

  STAGE(0, 0);
  for (int kt = 0; kt < 16; kt++) {
    const int cur = kt & 1;
    if (kt < 15) {
      STAGE(kt + 1, cur ^ 1);
      asm volatile("s_waitcnt vmcnt(4)" ::: "memory");  // tile kt done; kt+1 in flight
    } else {
      asm volatile("s_waitcnt vmcnt(0)" ::: "memory");
    }
    asm volatile("s_barrier" ::: "memory");             // tile kt visible to all

    // ---- K B-frags: read ONCE, reused across both q-subtiles ----
    bf16x8 kf[8];
#pragma unroll
    for (int ks = 0; ks < 2; ks++)
#pragma unroll
      for (int kc = 0; kc < 4; kc++)
        kf[ks*4 + kc] = *(const bf16x8*)&KsL[cur][(ks*32 + l31)*64 + ((kc*2 + h2) ^ sw)*8];

#pragma unroll
    for (int qs = 0; qs < 2; qs++) {
      f32x16 s0 = {}, s1 = {};
#pragma unroll
      for (int kc = 0; kc < 4; kc++) {
        s0 = __builtin_amdgcn_mfma_f32_32x32x16_bf16(qf[qs*4 + kc], kf[kc],     s0, 0, 0, 0);
        s1 = __builtin_amdgcn_mfma_f32_32x32x16_bf16(qf[qs*4 + kc], kf[4 + kc], s1, 0, 0, 0);
      }
#pragma unroll
      for (int i = 0; i < 16; i++) {
        float p0 = __builtin_amdgcn_exp2f(s0[i]);
        float p1 = __builtin_amdgcn_exp2f(s1[i]);
        lp[qs][i] += p0 + p1;
        int row = qs*32 + (i & 3) + 8*(i >> 2) + 4*h2;
        unsigned pk = (unsigned)f2bf(p0) | ((unsigned)f2bf(p1) << 16);
        *(unsigned*)&Ps[w][row*64 + 2*l31] = pk;
      }
    }

    // ---- V B-frags: read ONCE, reused across both q-subtiles ----
    bf16x8 vf[8];
#pragma unroll
    for (int ds = 0; ds < 2; ds++)
#pragma unroll
      for (int kc = 0; kc < 4; kc++)
        vf[ds*4 + kc] = *(const bf16x8*)&VtL[cur][(ds*32 + l31)*64 + ((kc*2 + h2) ^ sw)*8];

#pragma unroll
    for (int qs = 0; qs < 2; qs++) {
#pragma unroll
      for (int kc = 0; kc < 4; kc++) {
        bf16x8 pf = *(const bf16x8*)&Ps[w][(qs*32 + l31)*64 + kc*16 + h2*8];
        o[qs*2]     = __builtin_amdgcn_mfma_f32_32x32x16_bf16(pf, vf[kc],     o[qs*2],     0, 0, 0);
        o[qs*2 + 1] = __builtin_amdgcn_mfma_f32_32x32x16_bf16(pf, vf[4 + kc], o[qs*2 + 1], 0, 0, 0);
      }
    }

    asm volatile("s_barrier" ::: "memory");  // all waves done with buf[cur]
  }
#undef STAGE

  // ---- partial l reduction over the 32 col-lanes ----
#pragma unroll
  for (int qs = 0; qs < 2; qs++)
#pragma unroll
    for (int i = 0; i < 16; i++) {
#pragma unroll
      for (int mk = 1; mk < 32; mk <<= 1) lp[qs][i] += __shfl_xor(lp[qs][i], mk, 64);
    }

  // ---- store partials (bf16 o, fp32 l) ----
  ushort_t* op = (z == 0) ? op0 : op1;
  float* lwp = lw + (size_t)(z*32 + bh) * S_;
#pragma unroll
  for (int qs = 0; qs < 2; qs++)
#pragma unroll
    for (int i = 0; i < 16; i++) {
      int row = q0 + qs*32 + (i & 3) + 8*(i >> 2) + 4*h2;
      size_t base = ((size_t)bh * S_ + row) * 64;
      op[base + l31]      = f2bf(o[qs*2][i]);
      op[base + 32 + l31] = f2bf(o[qs*2 + 1][i]);
      if (l31 == 0) lwp[row] = lp[qs][i];
    }
}

// ---------------------------------------------------------------------------
// Combine split-K partials: att[b,s,h*64+d] = (o0+o1)/(l0+l1), bf16 out.
// ---------------------------------------------------------------------------
__global__ __launch_bounds__(256) void combine(const ushort_t* __restrict__ op0,
                                               const ushort_t* __restrict__ op1,
                                               const float* __restrict__ lw,
                                               ushort_t* __restrict__ att) {
  int tid = blockIdx.x * 256 + threadIdx.x;     // < 32*2048*8
  int d8 = (tid & 7) * 8;
  int s  = (tid >> 3) & (S_ - 1);
  int bh = tid >> 14;
  size_t pb = ((size_t)bh * S_ + s) * 64 + d8;
  uint4 a = *(const uint4*)(op0 + pb);
  uint4 b = *(const uint4*)(op1 + pb);
  float inv = 1.f / (lw[(size_t)bh * S_ + s] + lw[(size_t)(32 + bh) * S_ + s]);
  const ushort_t* as = (const ushort_t*)&a;
  const ushort_t* bs = (const ushort_t*)&b;
  ushort_t outv[8];
#pragma unroll
  for (int i = 0; i < 8; i++)
    outv[i] = f2bf((bf2f(as[i]) + bf2f(bs[i])) * inv);
  int bidx = bh >> 4, h = bh & 15;
  *(uint4*)(att + ((size_t)(bidx * S_ + s)) * D_ + h*64 + d8) = *(const uint4*)outv;
}

// ---------------------------------------------------------------------------
extern "C" void kernel_launch(void* const* d_in, const int* in_sizes, int n_in,
                              void* d_out, int out_size, void* d_ws, size_t ws_size,
                              hipStream_t stream) {
  (void)in_sizes; (void)n_in; (void)out_size; (void)ws_size;
  const float* x    = (const float*)d_in[0];
  const float* cosb = (const float*)d_in[1];
  const float* sinb = (const float*)d_in[2];
  const float* Wq   = (const float*)d_in[3];
  const float* Wk   = (const float*)d_in[4];
  const float* Wv   = (const float*)d_in[5];
  const float* Wo   = (const float*)d_in[6];
  float* out = (float*)d_out;

  ushort_t* w     = (ushort_t*)d_ws;
  ushort_t* xb    = w;                    // [4096][1024] bf16; reused as op0
  ushort_t* Wqkvt = w + 4194304;          // [3072][1024] bf16; base reused as lw
  ushort_t* Wot   = w + 7340032;          // [1024][1024] bf16
  ushort_t* Qb    = w + 8388608;          // (B,H,S,64): Q | K | V contiguous
  ushort_t* Kb    = w + 12582912;
  ushort_t* Vb    = w + 16777216;         // reused as op1
  ushort_t* Vtg   = w + 20971520;         // (B,H,64,S) interleaved
  ushort_t* att   = w + 25165824;         // (B,S,D) bf16
  float*    lw    = (float*)Wqkvt;        // 2*32*2048 fp32 partial-l

  convert_x<<<2048, 256, 0, stream>>>(x, xb);
  transpose_w<<<dim3(16, 16, 4), 256, 0, stream>>>(Wq, Wk, Wv, Wo, Wqkvt, Wot);

  // fused QKV projection + RoPE(Q,K) + scale fold; A-operand = weights
  gemm_bf16<1,128><<<dim3(32, 24), 256, 0, stream>>>(Wqkvt, xb, Qb, cosb, sinb);

  transpose_v<<<dim3(32, 32), 256, 0, stream>>>(Vb, Vtg);

  // split-K x2: op0 -> xb region, op1 -> Vb region, lw -> Wqkvt base
  attn32<<<dim3(8, 32, 2), 256, 0, stream>>>(Qb, Kb, Vtg, xb, Vb, lw);

  combine<<<2048, 256, 0, stream>>>(xb, Vb, lw, att);

  gemm_bf16<0,64><<<dim3(64, 8), 256, 0, stream>>>(Wot, att, out, nullptr, nullptr);
}

// Round 10
// 213.329 us; speedup vs baseline: 1.1710x; 1.1710x over previous
//
#include <hip/hip_runtime.h>

#define B_  2
#define S_  2048
#define D_  1024
#define H_  16
#define HD_ 64
#define M_  (B_*S_)

typedef __bf16 bf16x8 __attribute__((ext_vector_type(8)));
typedef float  f32x4  __attribute__((ext_vector_type(4)));
typedef float  f32x16 __attribute__((ext_vector_type(16)));
typedef unsigned short ushort_t;

static __device__ __forceinline__ ushort_t f2bf(float f) {
  __bf16 b = (__bf16)f;
  return __builtin_bit_cast(ushort_t, b);
}
static __device__ __forceinline__ float bf2f(ushort_t u) {
  return (float)__builtin_bit_cast(__bf16, u);
}

typedef __attribute__((address_space(1))) const unsigned u32g;
typedef __attribute__((address_space(3))) unsigned u32l;
// async global->LDS DMA, 16B/lane; LDS dest = wave-uniform base + lane*16
static __device__ __forceinline__ void gll16(const ushort_t* g, __bf16* l) {
  __builtin_amdgcn_global_load_lds((u32g*)g, (u32l*)l, 16, 0, 0);
}

// ---------------------------------------------------------------------------
// Fused prep: blocks 0..2047 convert x fp32->bf16; blocks 2048..3071 do the
// W transpose+convert (z = matrix, 16x16 64-tile grid).
// ---------------------------------------------------------------------------
__global__ __launch_bounds__(256) void prep(const float* __restrict__ x,
                                            ushort_t* __restrict__ xb,
                                            const float* __restrict__ Wq,
                                            const float* __restrict__ Wk,
                                            const float* __restrict__ Wv,
                                            const float* __restrict__ Wo,
                                            ushort_t* __restrict__ Wqkvt,
                                            ushort_t* __restrict__ Wot) {
  __shared__ __bf16 T[64][72];
  const int id = blockIdx.x, t = threadIdx.x;
  if (id < 2048) {
    size_t e = ((size_t)id * 256 + t) * 8;
    float4 a = *(const float4*)(x + e);
    float4 b = *(const float4*)(x + e + 4);
    uint4 pk;
    pk.x = (unsigned)f2bf(a.x) | ((unsigned)f2bf(a.y) << 16);
    pk.y = (unsigned)f2bf(a.z) | ((unsigned)f2bf(a.w) << 16);
    pk.z = (unsigned)f2bf(b.x) | ((unsigned)f2bf(b.y) << 16);
    pk.w = (unsigned)f2bf(b.z) | ((unsigned)f2bf(b.w) << 16);
    *(uint4*)(xb + e) = pk;
    return;
  }
  const int wid = id - 2048;
  const int z = wid >> 8, ky = (wid >> 4) & 15, nx = wid & 15;
  const float* W = (z == 0) ? Wq : (z == 1) ? Wk : (z == 2) ? Wv : Wo;
  ushort_t* Wt = (z < 3) ? (Wqkvt + (size_t)z * 1048576) : Wot;
  const int k0 = ky * 64, n0 = nx * 64;
  const int r = t >> 2, c16 = (t & 3) * 16;
#pragma unroll
  for (int i = 0; i < 4; i++) {
    float4 v = *(const float4*)(W + (size_t)(k0 + r) * D_ + n0 + c16 + i * 4);
    T[r][c16 + i*4 + 0] = (__bf16)v.x;
    T[r][c16 + i*4 + 1] = (__bf16)v.y;
    T[r][c16 + i*4 + 2] = (__bf16)v.z;
    T[r][c16 + i*4 + 3] = (__bf16)v.w;
  }
  __syncthreads();
  ushort_t vals[16];
#pragma unroll
  for (int i = 0; i < 16; i++) vals[i] = __builtin_bit_cast(ushort_t, T[c16 + i][r]);
  ushort_t* dst = Wt + (size_t)(n0 + r) * D_ + k0 + c16;
  *(uint4*)dst       = *(const uint4*)&vals[0];
  *(uint4*)(dst + 8) = *(const uint4*)&vals[8];
}

// ---------------------------------------------------------------------------
// V (B,H,S,64) bf16 -> Vtg (B,H,64,S) with key-interleave within each 64-key
// tile: column c holds key ((c&1)<<5)|(c>>1).  Must match attn32's P layout.
// ---------------------------------------------------------------------------
__global__ __launch_bounds__(256) void transpose_v(const ushort_t* __restrict__ Vb,
                                                   ushort_t* __restrict__ Vtg) {
  __shared__ __bf16 T[64][72];
  const int bh = blockIdx.y, kt = blockIdx.x;
  const int t = threadIdx.x, r = t >> 2, c16 = (t & 3) * 16;
  const ushort_t* src = Vb + ((size_t)bh * S_ + kt*64 + r) * 64 + c16;
  *(uint4*)&T[r][c16]     = *(const uint4*)src;
  *(uint4*)&T[r][c16 + 8] = *(const uint4*)(src + 8);
  __syncthreads();
  ushort_t vals[16];
#pragma unroll
  for (int i = 0; i < 16; i++) {
    int c = c16 + i;
    int k = ((c & 1) << 5) | (c >> 1);
    vals[i] = __builtin_bit_cast(ushort_t, T[k][r]);
  }
  ushort_t* dst = Vtg + ((size_t)bh * 64 + r) * S_ + kt*64 + c16;
  *(uint4*)dst       = *(const uint4*)&vals[0];
  *(uint4*)(dst + 8) = *(const uint4*)&vals[8];
}

// ---------------------------------------------------------------------------
// bf16 GEMM (m97 structure): C = A[M x 1024] @ Bt[N x 1024]^T.
// BM=128, BN=128 or 64, BK=32, 256 thr, 2x2 waves (wave tile 64 x BN/2).
// Staging via global_load_lds (unpadded LDS, lane-contiguous).
// OMODE 0: fp32 row-major out.  OMODE 1: bf16 scatter to Q/K/V (B,H,S,64),
// RoPE fused for Q (mat 0, + 0.125*log2e fold) and K (mat 1).
// ---------------------------------------------------------------------------
template<int OMODE, int BN>
__global__ __launch_bounds__(256) void gemm_bf16(const ushort_t* __restrict__ A,
                                                 const ushort_t* __restrict__ Bt,
                                                 void* __restrict__ Cp,
                                                 const float* __restrict__ cosb,
                                                 const float* __restrict__ sinb) {
  constexpr int NF = BN / 32;            // B-frags per wave (4 or 2)
  __shared__ __bf16 As[4096];            // [128][32]
  __shared__ __bf16 Bs[BN * 32];
  const int t = threadIdx.x, w = t >> 6, lane = t & 63, l15 = lane & 15, g = lane >> 4;
  const int wr = w >> 1, wc = w & 1;
  const int row0 = blockIdx.y * 128, col0 = blockIdx.x * BN;
  const int lr = t >> 2, lc = (t & 3) * 8;
  f32x4 acc[4][NF] = {};

  for (int k0 = 0; k0 < D_; k0 += 32) {
    __syncthreads();
#pragma unroll
    for (int i = 0; i < 2; i++)
      gll16(A + (size_t)(row0 + i*64 + lr) * D_ + k0 + lc, &As[i*2048 + w*512]);
#pragma unroll
    for (int i = 0; i < BN/64; i++)
      gll16(Bt + (size_t)(col0 + i*64 + lr) * D_ + k0 + lc, &Bs[i*2048 + w*512]);
    __syncthreads();
    bf16x8 af[4], bfv[NF];
#pragma unroll
    for (int mt = 0; mt < 4; mt++)  af[mt]  = *(const bf16x8*)&As[(wr*64 + mt*16 + l15)*32 + g*8];
#pragma unroll
    for (int nt = 0; nt < NF; nt++) bfv[nt] = *(const bf16x8*)&Bs[(wc*(BN/2) + nt*16 + l15)*32 + g*8];
#pragma unroll
    for (int mt = 0; mt < 4; mt++)
#pragma unroll
      for (int nt = 0; nt < NF; nt++)
        acc[mt][nt] = __builtin_amdgcn_mfma_f32_16x16x32_bf16(af[mt], bfv[nt], acc[mt][nt], 0, 0, 0);
  }

  if (OMODE == 0) {
#pragma unroll
    for (int mt = 0; mt < 4; mt++)
#pragma unroll
      for (int nt = 0; nt < NF; nt++) {
        int col = col0 + wc*(BN/2) + nt*16 + l15;
#pragma unroll
        for (int reg = 0; reg < 4; reg++) {
          int r = row0 + wr*64 + mt*16 + g*4 + reg;
          ((float*)Cp)[(size_t)r * D_ + col] = acc[mt][nt][reg];
        }
      }
  } else {
    const int mat = col0 >> 10;
    const int nc0 = (col0 + wc*64) & 1023;
    const int h = nc0 >> 6;
    ushort_t* dst = (ushort_t*)Cp + (size_t)mat * 4194304;
    const float QS = 0.125f * 1.4426950408889634f;
#pragma unroll
    for (int mt = 0; mt < 4; mt++) {
#pragma unroll
      for (int reg = 0; reg < 4; reg++) {
        int r = row0 + wr*64 + mt*16 + g*4 + reg;
        int b = r >> 11, s = r & (S_ - 1);
        size_t base = (((size_t)(b*H_ + h) * S_ + s) << 6);
        if (mat < 2) {   // Q or K: fused RoPE on fp32 acc
#pragma unroll
          for (int nt = 0; nt < 2; nt++) {
            int d1 = nt*16 + l15;
            float c  = cosb[s*32 + d1];
            float sn = sinb[s*32 + d1];
            float v1 = acc[mt][nt][reg], v2 = acc[mt][nt+2][reg];
            float r1 = v1*c - v2*sn;
            float r2 = v2*c + v1*sn;
            if (mat == 0) { r1 *= QS; r2 *= QS; }
            dst[base + d1]      = f2bf(r1);
            dst[base + d1 + 32] = f2bf(r2);
          }
        } else {
#pragma unroll
          for (int nt = 0; nt < 4; nt++)
            dst[base + nt*16 + l15] = f2bf(acc[mt][nt][reg]);
        }
      }
    }
  }
}

// ---------------------------------------------------------------------------
// Flash attention, split-K x2 (R6 structure + XOR-swizzled Ps):
//  - K/V staged via global_load_lds DMA, 128-key tiles, 2 compute phases
//  - all LDS unpadded with XOR swizzle chunk^=(row&7); Ps now swizzled too
//    (R6's Ps[32][72] stride aliased rows {r,r+8,r+16,r+24} -> 4-way conflict
//    on every P A-frag read = the measured 4.2M conflict cycles)
//  - fixed-max softmax (exact by shift invariance), deferred l reduction
// LDS: Ks 16K + Vt 16K + Ps 16K = 48 KB -> 3 blocks/CU.
// C/D 32x32 (m74/m101): col=lane&31, row=(reg&3)+8*(reg>>2)+4*(lane>>5).
// ---------------------------------------------------------------------------
__global__ __launch_bounds__(256) void attn32(const ushort_t* __restrict__ Q,
                                              const ushort_t* __restrict__ K,
                                              const ushort_t* __restrict__ Vtg,
                                              ushort_t* __restrict__ op0,
                                              ushort_t* __restrict__ op1,
                                              float* __restrict__ lw) {
  __shared__ __bf16 KsL[128 * 64];   // [key][d] 128B rows, swizzled chunks
  __shared__ __bf16 VtL[64 * 128];   // [d][key] 256B rows, swizzled chunks
  __shared__ __bf16 Ps[4][32 * 64];  // per-wave P, swizzled chunks
  const int t = threadIdx.x, w = t >> 6, lane = t & 63;
  const int l31 = lane & 31, h2 = lane >> 5, sw = l31 & 7;
  const int bh = blockIdx.y, q0 = blockIdx.x * 128 + w * 32, z = blockIdx.z;

  const ushort_t* Qp = Q + ((size_t)bh * S_ + q0 + l31) * HD_;
  bf16x8 qf[4];
#pragma unroll
  for (int kc = 0; kc < 4; kc++) qf[kc] = *(const bf16x8*)(Qp + kc*16 + h2*8);

  f32x16 o0 = {}, o1 = {};
  float lp[16];
#pragma unroll
  for (int i = 0; i < 16; i++) lp[i] = 0.f;

  const ushort_t* Kb = K   + ((size_t)bh * S_ + z * 1024) * HD_;
  const ushort_t* Vg = Vtg + (size_t)bh * HD_ * S_ + z * 1024;  // [d][s-int]
  const int krl = lane >> 3;                  // row-in-DMA 0..7
  const int kco = ((lane & 7) ^ krl) * 8;     // K swizzled source chunk
  const int vrl = lane >> 4;                  // V row-in-DMA 0..3

  for (int kt = 0; kt < 8; kt++) {            // 8 x 128-key tiles
    __syncthreads();
#pragma unroll
    for (int p = 0; p < 4; p++) {             // K tile 128x64
      int bk = w*8 + p*32;
      gll16(Kb + (size_t)(kt*128 + bk + krl) * HD_ + kco, &KsL[bk*64]);
    }
#pragma unroll
    for (int p = 0; p < 4; p++) {             // V tile 64x128
      int bd = w*4 + p*16;
      int d  = bd + vrl;
      int cd = (lane & 8) | ((lane & 7) ^ (d & 7));
      gll16(Vg + (size_t)d * S_ + kt*128 + cd*8, &VtL[bd*128]);
    }
    __syncthreads();

#pragma unroll
    for (int ph = 0; ph < 2; ph++) {          // 2 x 64-key phases
      // ---- QK^T ----
      f32x16 s0 = {}, s1 = {};
#pragma unroll
      for (int kc = 0; kc < 4; kc++) {
        int cs = ((kc*2 + h2) ^ sw) * 8;
        bf16x8 b0 = *(const bf16x8*)&KsL[(ph*64 + l31)*64      + cs];
        bf16x8 b1 = *(const bf16x8*)&KsL[(ph*64 + 32 + l31)*64 + cs];
        s0 = __builtin_amdgcn_mfma_f32_32x32x16_bf16(qf[kc], b0, s0, 0, 0, 0);
        s1 = __builtin_amdgcn_mfma_f32_32x32x16_bf16(qf[kc], b1, s1, 0, 0, 0);
      }

      // ---- p = exp2(s); packed b32 store, XOR-swizzled chunk ----
#pragma unroll
      for (int i = 0; i < 16; i++) {
        float p0 = __builtin_amdgcn_exp2f(s0[i]);
        float p1 = __builtin_amdgcn_exp2f(s1[i]);
        lp[i] += p0 + p1;
        int row = (i & 3) + 8*(i >> 2) + 4*h2;
        unsigned pk = (unsigned)f2bf(p0) | ((unsigned)f2bf(p1) << 16);
        *(unsigned*)&Ps[w][row*64 + ((l31 >> 2) ^ (row & 7))*8 + (l31 & 3)*2] = pk;
      }

      // ---- PV ----
#pragma unroll
      for (int kc = 0; kc < 4; kc++) {
        int cs = ((kc*2 + h2) ^ sw) * 8;
        bf16x8 pf = *(const bf16x8*)&Ps[w][l31*64 + cs];
        bf16x8 v0 = *(const bf16x8*)&VtL[l31*128      + (ph*8 | ((kc*2 + h2) ^ sw))*8];
        bf16x8 v1 = *(const bf16x8*)&VtL[(32 + l31)*128 + (ph*8 | ((kc*2 + h2) ^ sw))*8];
        o0 = __builtin_amdgcn_mfma_f32_32x32x16_bf16(pf, v0, o0, 0, 0, 0);
        o1 = __builtin_amdgcn_mfma_f32_32x32x16_bf16(pf, v1, o1, 0, 0, 0);
      }
    }
  }

  // ---- partial l reduction over the 32 col-lanes ----
#pragma unroll
  for (int i = 0; i < 16; i++) {
#pragma unroll
    for (int mk = 1; mk < 32; mk <<= 1) lp[i] += __shfl_xor(lp[i], mk, 64);
  }

  // ---- store partials (bf16 o, fp32 l) ----
  ushort_t* op = (z == 0) ? op0 : op1;
  float* lwp = lw + (size_t)(z*32 + bh) * S_;
#pragma unroll
  for (int i = 0; i < 16; i++) {
    int row = q0 + (i & 3) + 8*(i >> 2) + 4*h2;
    size_t base = ((size_t)bh * S_ + row) * 64;
    op[base + l31]      = f2bf(o0[i]);
    op[base + 32 + l31] = f2bf(o1[i]);
    if (l31 == 0) lwp[row] = lp[i];
  }
}

// ---------------------------------------------------------------------------
// Combine split-K partials: att[b,s,h*64+d] = (o0+o1)/(l0+l1), bf16 out.
// ---------------------------------------------------------------------------
__global__ __launch_bounds__(256) void combine(const ushort_t* __restrict__ op0,
                                               const ushort_t* __restrict__ op1,
                                               const float* __restrict__ lw,
                                               ushort_t* __restrict__ att) {
  int tid = blockIdx.x * 256 + threadIdx.x;     // < 32*2048*8
  int d8 = (tid & 7) * 8;
  int s  = (tid >> 3) & (S_ - 1);
  int bh = tid >> 14;
  size_t pb = ((size_t)bh * S_ + s) * 64 + d8;
  uint4 a = *(const uint4*)(op0 + pb);
  uint4 b = *(const uint4*)(op1 + pb);
  float inv = 1.f / (lw[(size_t)bh * S_ + s] + lw[(size_t)(32 + bh) * S_ + s]);
  const ushort_t* as = (const ushort_t*)&a;
  const ushort_t* bs = (const ushort_t*)&b;
  ushort_t outv[8];
#pragma unroll
  for (int i = 0; i < 8; i++)
    outv[i] = f2bf((bf2f(as[i]) + bf2f(bs[i])) * inv);
  int bidx = bh >> 4, h = bh & 15;
  *(uint4*)(att + ((size_t)(bidx * S_ + s)) * D_ + h*64 + d8) = *(const uint4*)outv;
}

// ---------------------------------------------------------------------------
extern "C" void kernel_launch(void* const* d_in, const int* in_sizes, int n_in,
                              void* d_out, int out_size, void* d_ws, size_t ws_size,
                              hipStream_t stream) {
  (void)in_sizes; (void)n_in; (void)out_size; (void)ws_size;
  const float* x    = (const float*)d_in[0];
  const float* cosb = (const float*)d_in[1];
  const float* sinb = (const float*)d_in[2];
  const float* Wq   = (const float*)d_in[3];
  const float* Wk   = (const float*)d_in[4];
  const float* Wv   = (const float*)d_in[5];
  const float* Wo   = (const float*)d_in[6];
  float* out = (float*)d_out;

  ushort_t* w     = (ushort_t*)d_ws;
  ushort_t* xb    = w;                    // [4096][1024] bf16; reused as op0
  ushort_t* Wqkvt = w + 4194304;          // [3072][1024] bf16; base reused as lw
  ushort_t* Wot   = w + 7340032;          // [1024][1024] bf16
  ushort_t* Qb    = w + 8388608;          // (B,H,S,64): Q | K | V contiguous
  ushort_t* Kb    = w + 12582912;
  ushort_t* Vb    = w + 16777216;         // reused as op1
  ushort_t* Vtg   = w + 20971520;         // (B,H,64,S) interleaved
  ushort_t* att   = w + 25165824;         // (B,S,D) bf16
  float*    lw    = (float*)Wqkvt;        // 2*32*2048 fp32 partial-l

  prep<<<3072, 256, 0, stream>>>(x, xb, Wq, Wk, Wv, Wo, Wqkvt, Wot);

  // fused QKV projection + RoPE(Q,K) + scale fold   (consumes xb, Wqkvt)
  gemm_bf16<1,128><<<dim3(24, 32), 256, 0, stream>>>(xb, Wqkvt, Qb, cosb, sinb);

  transpose_v<<<dim3(32, 32), 256, 0, stream>>>(Vb, Vtg);   // consumes Vb

  // split-K x2: op0 -> xb region, op1 -> Vb region, lw -> Wqkvt base
  attn32<<<dim3(16, 32, 2), 256, 0, stream>>>(Qb, Kb, Vtg, xb, Vb, lw);

  combine<<<2048, 256, 0, stream>>>(xb, Vb, lw, att);

  gemm_bf16<0,64><<<dim3(16, 32), 256, 0, stream>>>(att, Wot, out, nullptr, nullptr);
}